// Round 1
// baseline (352.723 us; speedup 1.0000x reference)
//
#include <hip/hip_runtime.h>
#include <hip/hip_bf16.h>

#define NTOK 8192
#define DIM 512
#define HID 1024
#define NE 16
#define CAP 1280   // per-expert capacity; mean load = 1024, sigma ~30 -> +8.5 sigma headroom

typedef __attribute__((ext_vector_type(8))) short short8;
typedef __attribute__((ext_vector_type(4))) float f32x4;

static __device__ __forceinline__ unsigned short f2bf(float f) {
    __hip_bfloat16 h = __float2bfloat16(f);
    return __builtin_bit_cast(unsigned short, h);
}

// src: [R][C] fp32 (one expert per blockIdx.z) -> dst: [C][R] bf16
__global__ void transpose_cvt(const float* __restrict__ src, unsigned short* __restrict__ dst,
                              int R, int C) {
    __shared__ float tile[32][33];
    int e = blockIdx.z;
    src += (size_t)e * R * C;
    dst += (size_t)e * R * C;
    int c0 = blockIdx.x * 32, r0 = blockIdx.y * 32;
    int tx = threadIdx.x, ty = threadIdx.y;  // (32,8)
    #pragma unroll
    for (int i = 0; i < 32; i += 8)
        tile[ty + i][tx] = src[(size_t)(r0 + ty + i) * C + c0 + tx];
    __syncthreads();
    #pragma unroll
    for (int i = 0; i < 32; i += 8)
        dst[(size_t)(c0 + ty + i) * R + r0 + tx] = f2bf(tile[tx][ty + i]);
}

__global__ void route_fill(const float* __restrict__ routing, int* __restrict__ cnt,
                           int* __restrict__ idx, float* __restrict__ wtb) {
    int i = blockIdx.x * blockDim.x + threadIdx.x;  // over N*E, row-major [n][e]
    if (i >= NTOK * NE) return;
    float r = routing[i];
    if (r != 0.0f) {
        int n = i >> 4, e = i & 15;
        int pos = atomicAdd(&cnt[e], 1);
        if (pos < CAP) {
            idx[e * CAP + pos] = n;
            wtb[e * CAP + pos] = r;
        }
    }
}

// one block (128 thr) per (expert,row); valid rows gathered+converted, pad rows zeroed
__global__ void gather_x(const float* __restrict__ x, const int* __restrict__ cnt,
                         const int* __restrict__ idx, unsigned short* __restrict__ xg) {
    int b = blockIdx.x;              // e*CAP + row
    int e = b / CAP, row = b - e * CAP;
    int t = threadIdx.x;             // 128 threads * 4 floats = 512
    int c = cnt[e]; c = c > CAP ? CAP : c;
    ushort4 o;
    if (row < c) {
        int n = idx[b];
        float4 v = ((const float4*)(x + (size_t)n * DIM))[t];
        o.x = f2bf(v.x); o.y = f2bf(v.y); o.z = f2bf(v.z); o.w = f2bf(v.w);
    } else {
        o.x = 0; o.y = 0; o.z = 0; o.w = 0;
    }
    ((ushort4*)(xg + (size_t)b * DIM))[t] = o;
}

// 128x128 tile, BK=64, 4 waves (2x2), each wave 4x4 grid of 16x16x32 bf16 MFMA.
// A: MxK row-major (lda=K), B: NxK row-major i.e. B^T layout (ldb=K).
template <int K>
__device__ __forceinline__ void mfma_main(const unsigned short* __restrict__ A,
                                          const unsigned short* __restrict__ B,
                                          unsigned short* As, unsigned short* Bs,
                                          f32x4 acc[4][4]) {
    int t = threadIdx.x;
    int wave = t >> 6, lane = t & 63;
    int wm = wave >> 1, wn = wave & 1;
    int quad = lane >> 4, l16 = lane & 15;
    for (int kc = 0; kc < K; kc += 64) {
        __syncthreads();
        #pragma unroll
        for (int i = 0; i < 4; i++) {
            int id = i * 256 + t;
            int row = id >> 3, col = (id & 7) * 8;
            *(uint4*)(&As[row * 64 + col]) = *(const uint4*)(A + (size_t)row * K + kc + col);
            *(uint4*)(&Bs[row * 64 + col]) = *(const uint4*)(B + (size_t)row * K + kc + col);
        }
        __syncthreads();
        #pragma unroll
        for (int kk = 0; kk < 64; kk += 32) {
            short8 av[4], bv[4];
            #pragma unroll
            for (int mt = 0; mt < 4; mt++)
                av[mt] = *(const short8*)(&As[(wm * 64 + mt * 16 + l16) * 64 + kk + quad * 8]);
            #pragma unroll
            for (int nt = 0; nt < 4; nt++)
                bv[nt] = *(const short8*)(&Bs[(wn * 64 + nt * 16 + l16) * 64 + kk + quad * 8]);
            #pragma unroll
            for (int mt = 0; mt < 4; mt++)
                #pragma unroll
                for (int nt = 0; nt < 4; nt++)
                    acc[mt][nt] = __builtin_amdgcn_mfma_f32_16x16x32_bf16(
                        av[mt], bv[nt], acc[mt][nt], 0, 0, 0);
        }
    }
}

__global__ __launch_bounds__(256) void gemm1_gelu(
    const unsigned short* __restrict__ xg, const unsigned short* __restrict__ w1t,
    const float* __restrict__ b1, const int* __restrict__ cnt,
    unsigned short* __restrict__ hbuf) {
    __shared__ __align__(16) unsigned short As[128 * 64];
    __shared__ __align__(16) unsigned short Bs[128 * 64];
    int e = blockIdx.z;
    int c = cnt[e]; c = c > CAP ? CAP : c;
    int m0 = blockIdx.y * 128;
    if (m0 >= c) return;
    int n0 = blockIdx.x * 128;
    const unsigned short* A = xg + ((size_t)e * CAP + m0) * DIM;
    const unsigned short* B = w1t + ((size_t)e * HID + n0) * DIM;
    f32x4 z = {0.f, 0.f, 0.f, 0.f};
    f32x4 acc[4][4];
    #pragma unroll
    for (int mt = 0; mt < 4; mt++)
        #pragma unroll
        for (int nt = 0; nt < 4; nt++) acc[mt][nt] = z;
    mfma_main<DIM>(A, B, As, Bs, acc);
    int t = threadIdx.x;
    int wave = t >> 6, lane = t & 63;
    int wm = wave >> 1, wn = wave & 1, quad = lane >> 4, l16 = lane & 15;
    #pragma unroll
    for (int nt = 0; nt < 4; nt++) {
        int gn = n0 + wn * 64 + nt * 16 + l16;
        float bias = b1[e * HID + gn];
        #pragma unroll
        for (int mt = 0; mt < 4; mt++) {
            #pragma unroll
            for (int r = 0; r < 4; r++) {
                int gm = m0 + wm * 64 + mt * 16 + quad * 4 + r;
                float v = acc[mt][nt][r] + bias;
                float g = 0.5f * v * (1.0f + erff(v * 0.70710678118654752f));  // exact GELU
                hbuf[((size_t)e * CAP + gm) * HID + gn] = f2bf(g);
            }
        }
    }
}

__global__ __launch_bounds__(256) void gemm2_scatter(
    const unsigned short* __restrict__ hbuf, const unsigned short* __restrict__ w2t,
    const float* __restrict__ b2, const int* __restrict__ cnt,
    const int* __restrict__ idx, const float* __restrict__ wtb,
    float* __restrict__ out) {
    __shared__ __align__(16) unsigned short As[128 * 64];
    __shared__ __align__(16) unsigned short Bs[128 * 64];
    int e = blockIdx.z;
    int c = cnt[e]; c = c > CAP ? CAP : c;
    int m0 = blockIdx.y * 128;
    if (m0 >= c) return;
    int n0 = blockIdx.x * 128;
    const unsigned short* A = hbuf + ((size_t)e * CAP + m0) * HID;
    const unsigned short* B = w2t + ((size_t)e * DIM + n0) * HID;
    f32x4 z = {0.f, 0.f, 0.f, 0.f};
    f32x4 acc[4][4];
    #pragma unroll
    for (int mt = 0; mt < 4; mt++)
        #pragma unroll
        for (int nt = 0; nt < 4; nt++) acc[mt][nt] = z;
    mfma_main<HID>(A, B, As, Bs, acc);
    int t = threadIdx.x;
    int wave = t >> 6, lane = t & 63;
    int wm = wave >> 1, wn = wave & 1, quad = lane >> 4, l16 = lane & 15;
    #pragma unroll
    for (int mt = 0; mt < 4; mt++) {
        #pragma unroll
        for (int r = 0; r < 4; r++) {
            int gm = m0 + wm * 64 + mt * 16 + quad * 4 + r;
            if (gm < c) {
                int tok = idx[e * CAP + gm];
                float w = wtb[e * CAP + gm];
                #pragma unroll
                for (int nt = 0; nt < 4; nt++) {
                    int gn = n0 + wn * 64 + nt * 16 + l16;
                    float v = acc[mt][nt][r] + b2[e * DIM + gn];
                    atomicAdd(&out[(size_t)tok * DIM + gn], w * v);
                }
            }
        }
    }
}

extern "C" void kernel_launch(void* const* d_in, const int* in_sizes, int n_in,
                              void* d_out, int out_size, void* d_ws, size_t ws_size,
                              hipStream_t stream) {
    const float* x       = (const float*)d_in[0];
    const float* routing = (const float*)d_in[1];
    const float* W1      = (const float*)d_in[2];
    const float* b1      = (const float*)d_in[3];
    const float* W2      = (const float*)d_in[4];
    const float* b2      = (const float*)d_in[5];
    float* out = (float*)d_out;

    // workspace carve (ws is poisoned 0xAA every call -> init what we need)
    char* w = (char*)d_ws;
    int*   cnt = (int*)w;                                   // 64 B (reserve 256)
    int*   idx = (int*)(w + 256);                           // NE*CAP*4
    float* wtb = (float*)(w + 256 + NE * CAP * 4);          // NE*CAP*4
    char* base = w + 256 + NE * CAP * 8;                    // 164,096 B (256-aligned)
    unsigned short* xg  = (unsigned short*)base;            // NE*CAP*DIM bf16 = 20 MiB
    unsigned short* hb  = xg + (size_t)NE * CAP * DIM;      // NE*CAP*HID bf16 = 40 MiB
    unsigned short* w1t = hb + (size_t)NE * CAP * HID;      // NE*HID*DIM bf16 = 16 MiB
    unsigned short* w2t = w1t + (size_t)NE * HID * DIM;     // NE*DIM*HID bf16 = 16 MiB

    hipMemsetAsync(cnt, 0, 256, stream);
    hipMemsetAsync(d_out, 0, (size_t)out_size * 4, stream);

    // W1[e]: [DIM][HID] -> w1t[e]: [HID][DIM] (bf16, K-contig)
    transpose_cvt<<<dim3(HID / 32, DIM / 32, NE), dim3(32, 8), 0, stream>>>(W1, w1t, DIM, HID);
    // W2[e]: [HID][DIM] -> w2t[e]: [DIM][HID] (bf16, K-contig)
    transpose_cvt<<<dim3(DIM / 32, HID / 32, NE), dim3(32, 8), 0, stream>>>(W2, w2t, HID, DIM);

    route_fill<<<(NTOK * NE) / 256, 256, 0, stream>>>(routing, cnt, idx, wtb);
    gather_x<<<NE * CAP, 128, 0, stream>>>(x, cnt, idx, xg);

    gemm1_gelu<<<dim3(HID / 128, CAP / 128, NE), 256, 0, stream>>>(xg, w1t, b1, cnt, hb);
    gemm2_scatter<<<dim3(DIM / 128, CAP / 128, NE), 256, 0, stream>>>(hb, w2t, b2, cnt, idx, wtb, out);
}

// Round 2
// 288.363 us; speedup vs baseline: 1.2232x; 1.2232x over previous
//
#include <hip/hip_runtime.h>
#include <hip/hip_bf16.h>

#define NTOK 8192
#define DIM 512
#define HID 1024
#define NE 16
#define CAP 1280   // per-expert capacity; mean load = 1024, sigma ~30

typedef __attribute__((ext_vector_type(8))) short short8;
typedef __attribute__((ext_vector_type(4))) float f32x4;

static __device__ __forceinline__ unsigned short f2bf(float f) {
    __hip_bfloat16 h = __float2bfloat16(f);
    return __builtin_bit_cast(unsigned short, h);
}

// async global->LDS, 16B per lane; LDS dst = wave-uniform base + lane*16
static __device__ __forceinline__ void gl_lds16(const unsigned short* g, unsigned short* l) {
    __builtin_amdgcn_global_load_lds(
        (const __attribute__((address_space(1))) unsigned int*)g,
        (__attribute__((address_space(3))) unsigned int*)l, 16, 0, 0);
}

// src: [R][C] fp32 (one expert per blockIdx.z) -> dst: [C][R] bf16
__global__ void transpose_cvt(const float* __restrict__ src, unsigned short* __restrict__ dst,
                              int R, int C) {
    __shared__ float tile[32][33];
    int e = blockIdx.z;
    src += (size_t)e * R * C;
    dst += (size_t)e * R * C;
    int c0 = blockIdx.x * 32, r0 = blockIdx.y * 32;
    int tx = threadIdx.x, ty = threadIdx.y;  // (32,8)
    #pragma unroll
    for (int i = 0; i < 32; i += 8)
        tile[ty + i][tx] = src[(size_t)(r0 + ty + i) * C + c0 + tx];
    __syncthreads();
    #pragma unroll
    for (int i = 0; i < 32; i += 8)
        dst[(size_t)(c0 + ty + i) * R + r0 + tx] = f2bf(tile[tx][ty + i]);
}

// one thread per token: scan its 16 scores, assign slot 0/1 in e-order
__global__ void route_fill(const float* __restrict__ routing, int* __restrict__ cnt,
                           int* __restrict__ sidx, float* __restrict__ wtb) {
    int n = blockIdx.x * blockDim.x + threadIdx.x;
    if (n >= NTOK) return;
    int slot = 0;
    #pragma unroll
    for (int e = 0; e < NE; e++) {
        float r = routing[n * NE + e];
        if (r != 0.0f) {
            if (slot < 2) {
                int pos = atomicAdd(&cnt[e], 1);
                if (pos < CAP) {
                    sidx[e * CAP + pos] = n * 2 + slot;
                    wtb[e * CAP + pos] = r;
                }
            }
            slot++;
        }
    }
}

// one block (128 thr) per (expert,row); valid rows gathered+converted, pad rows zeroed
__global__ void gather_x(const float* __restrict__ x, const int* __restrict__ cnt,
                         const int* __restrict__ sidx, unsigned short* __restrict__ xg) {
    int b = blockIdx.x;              // e*CAP + row
    int e = b / CAP, row = b - e * CAP;
    int t = threadIdx.x;             // 128 threads * 4 floats = 512
    int c = cnt[e]; c = c > CAP ? CAP : c;
    ushort4 o;
    if (row < c) {
        int n = sidx[b] >> 1;
        float4 v = ((const float4*)(x + (size_t)n * DIM))[t];
        o.x = f2bf(v.x); o.y = f2bf(v.y); o.z = f2bf(v.z); o.w = f2bf(v.w);
    } else {
        o.x = 0; o.y = 0; o.z = 0; o.w = 0;
    }
    ((ushort4*)(xg + (size_t)b * DIM))[t] = o;
}

// 128x128 tile, BK=64, 4 waves (2x2), each wave 4x4 of 16x16x32 bf16 MFMA.
// A: MxK row-major, B: NxK row-major (both K-contig). LDS XOR-swizzled:
// logical chunk c (8 elems) of row r lives at physical chunk c ^ (r&7).
template <int K>
__device__ __forceinline__ void mfma_main(const unsigned short* __restrict__ A,
                                          const unsigned short* __restrict__ B,
                                          unsigned short* As, unsigned short* Bs,
                                          f32x4 acc[4][4]) {
    int t = threadIdx.x;
    int wave = t >> 6, lane = t & 63;
    int wm = wave >> 1, wn = wave & 1;
    int quad = lane >> 4, l16 = lane & 15;
    int lr = lane >> 3;                 // row within 8-row staging group
    int lp = lane & 7;                  // physical chunk this lane deposits
    int col = (lp ^ lr) << 3;           // logical element col for this lane's load
    int rs = l16 & 7;                   // read-side swizzle key (== row&7)
    int pA0 = (quad ^ rs) << 3;         // kk=0 physical chunk offset (elems)
    int pA1 = ((quad + 4) ^ rs) << 3;   // kk=32
    for (int kc = 0; kc < K; kc += 64) {
        __syncthreads();
        #pragma unroll
        for (int j = 0; j < 4; j++) {
            int rb = wave * 32 + j * 8;
            gl_lds16(A + (size_t)(rb + lr) * K + kc + col, As + rb * 64);
            gl_lds16(B + (size_t)(rb + lr) * K + kc + col, Bs + rb * 64);
        }
        __syncthreads();
        #pragma unroll
        for (int kk = 0; kk < 64; kk += 32) {
            int po = kk ? pA1 : pA0;
            short8 av[4], bv[4];
            #pragma unroll
            for (int mt = 0; mt < 4; mt++)
                av[mt] = *(const short8*)(&As[(wm * 64 + mt * 16 + l16) * 64 + po]);
            #pragma unroll
            for (int nt = 0; nt < 4; nt++)
                bv[nt] = *(const short8*)(&Bs[(wn * 64 + nt * 16 + l16) * 64 + po]);
            #pragma unroll
            for (int mt = 0; mt < 4; mt++)
                #pragma unroll
                for (int nt = 0; nt < 4; nt++)
                    acc[mt][nt] = __builtin_amdgcn_mfma_f32_16x16x32_bf16(
                        av[mt], bv[nt], acc[mt][nt], 0, 0, 0);
        }
    }
}

__global__ __launch_bounds__(256) void gemm1_gelu(
    const unsigned short* __restrict__ xg, const unsigned short* __restrict__ w1t,
    const float* __restrict__ b1, const int* __restrict__ cnt,
    unsigned short* __restrict__ hbuf) {
    __shared__ __align__(16) unsigned short As[128 * 64];
    __shared__ __align__(16) unsigned short Bs[128 * 64];
    int e = blockIdx.z;
    int c = cnt[e]; c = c > CAP ? CAP : c;
    int m0 = blockIdx.y * 128;
    if (m0 >= c) return;
    int n0 = blockIdx.x * 128;
    const unsigned short* A = xg + ((size_t)e * CAP + m0) * DIM;
    const unsigned short* B = w1t + ((size_t)e * HID + n0) * DIM;
    f32x4 z = {0.f, 0.f, 0.f, 0.f};
    f32x4 acc[4][4];
    #pragma unroll
    for (int mt = 0; mt < 4; mt++)
        #pragma unroll
        for (int nt = 0; nt < 4; nt++) acc[mt][nt] = z;
    mfma_main<DIM>(A, B, As, Bs, acc);
    int t = threadIdx.x;
    int wave = t >> 6, lane = t & 63;
    int wm = wave >> 1, wn = wave & 1, quad = lane >> 4, l16 = lane & 15;
    #pragma unroll
    for (int nt = 0; nt < 4; nt++) {
        int gn = n0 + wn * 64 + nt * 16 + l16;
        float bias = b1[e * HID + gn];
        #pragma unroll
        for (int mt = 0; mt < 4; mt++) {
            #pragma unroll
            for (int r = 0; r < 4; r++) {
                int gm = m0 + wm * 64 + mt * 16 + quad * 4 + r;
                float v = acc[mt][nt][r] + bias;
                float g = 0.5f * v * (1.0f + erff(v * 0.70710678118654752f));  // exact GELU
                hbuf[((size_t)e * CAP + gm) * HID + gn] = f2bf(g);
            }
        }
    }
}

__global__ __launch_bounds__(256) void gemm2_store(
    const unsigned short* __restrict__ hbuf, const unsigned short* __restrict__ w2t,
    const float* __restrict__ b2, const int* __restrict__ cnt,
    const int* __restrict__ sidx, const float* __restrict__ wtb,
    float* __restrict__ ybuf) {
    __shared__ __align__(16) unsigned short As[128 * 64];
    __shared__ __align__(16) unsigned short Bs[128 * 64];
    int e = blockIdx.z;
    int c = cnt[e]; c = c > CAP ? CAP : c;
    int m0 = blockIdx.y * 128;
    if (m0 >= c) return;
    int n0 = blockIdx.x * 128;
    const unsigned short* A = hbuf + ((size_t)e * CAP + m0) * HID;
    const unsigned short* B = w2t + ((size_t)e * DIM + n0) * HID;
    f32x4 z = {0.f, 0.f, 0.f, 0.f};
    f32x4 acc[4][4];
    #pragma unroll
    for (int mt = 0; mt < 4; mt++)
        #pragma unroll
        for (int nt = 0; nt < 4; nt++) acc[mt][nt] = z;
    mfma_main<HID>(A, B, As, Bs, acc);
    int t = threadIdx.x;
    int wave = t >> 6, lane = t & 63;
    int wm = wave >> 1, wn = wave & 1, quad = lane >> 4, l16 = lane & 15;
    #pragma unroll
    for (int mt = 0; mt < 4; mt++) {
        #pragma unroll
        for (int r = 0; r < 4; r++) {
            int gm = m0 + wm * 64 + mt * 16 + quad * 4 + r;
            if (gm < c) {
                int si = sidx[e * CAP + gm];       // token*2 + slot
                float wgt = wtb[e * CAP + gm];
                float* yrow = ybuf + (size_t)si * DIM;
                #pragma unroll
                for (int nt = 0; nt < 4; nt++) {
                    int gn = n0 + wn * 64 + nt * 16 + l16;
                    yrow[gn] = wgt * (acc[mt][nt][r] + b2[e * DIM + gn]);
                }
            }
        }
    }
}

// out[n] = ybuf[n*2] + ybuf[n*2+1]
__global__ void combine(const float* __restrict__ yb, float* __restrict__ out) {
    int i = blockIdx.x * 256 + threadIdx.x;   // over NTOK * DIM/4
    int n = i >> 7, d4 = i & 127;             // DIM/4 = 128
    float4 a = ((const float4*)(yb + (size_t)(2 * n) * DIM))[d4];
    float4 b = ((const float4*)(yb + (size_t)(2 * n + 1) * DIM))[d4];
    float4 o;
    o.x = a.x + b.x; o.y = a.y + b.y; o.z = a.z + b.z; o.w = a.w + b.w;
    ((float4*)(out + (size_t)n * DIM))[d4] = o;
}

extern "C" void kernel_launch(void* const* d_in, const int* in_sizes, int n_in,
                              void* d_out, int out_size, void* d_ws, size_t ws_size,
                              hipStream_t stream) {
    const float* x       = (const float*)d_in[0];
    const float* routing = (const float*)d_in[1];
    const float* W1      = (const float*)d_in[2];
    const float* b1      = (const float*)d_in[3];
    const float* W2      = (const float*)d_in[4];
    const float* b2      = (const float*)d_in[5];
    float* out = (float*)d_out;

    // workspace carve (ws poisoned 0xAA each call)
    char* w = (char*)d_ws;
    int*   cnt  = (int*)w;                                  // 256 B
    int*   sidx = (int*)(w + 256);                          // NE*CAP*4
    float* wtb  = (float*)(w + 256 + NE * CAP * 4);         // NE*CAP*4
    char* base = w + 256 + NE * CAP * 8;
    unsigned short* xg  = (unsigned short*)base;            // 20 MiB
    unsigned short* hb  = xg + (size_t)NE * CAP * DIM;      // 40 MiB
    unsigned short* w1t = hb + (size_t)NE * CAP * HID;      // 16 MiB
    unsigned short* w2t = w1t + (size_t)NE * HID * DIM;     // 16 MiB
    float* ybuf = (float*)(w2t + (size_t)NE * DIM * HID);   // 32 MiB fp32 [NTOK][2][DIM]

    hipMemsetAsync(cnt, 0, 256, stream);
    hipMemsetAsync(ybuf, 0, (size_t)NTOK * 2 * DIM * 4, stream);

    transpose_cvt<<<dim3(HID / 32, DIM / 32, NE), dim3(32, 8), 0, stream>>>(W1, w1t, DIM, HID);
    transpose_cvt<<<dim3(DIM / 32, HID / 32, NE), dim3(32, 8), 0, stream>>>(W2, w2t, HID, DIM);

    route_fill<<<NTOK / 256, 256, 0, stream>>>(routing, cnt, sidx, wtb);
    gather_x<<<NE * CAP, 128, 0, stream>>>(x, cnt, sidx, xg);

    gemm1_gelu<<<dim3(HID / 128, CAP / 128, NE), 256, 0, stream>>>(xg, w1t, b1, cnt, hb);
    gemm2_store<<<dim3(DIM / 128, CAP / 128, NE), 256, 0, stream>>>(hb, w2t, b2, cnt, sidx, wtb, ybuf);
    combine<<<(NTOK * DIM / 4) / 256, 256, 0, stream>>>(ybuf, out);
}

// Round 3
// 274.496 us; speedup vs baseline: 1.2850x; 1.0505x over previous
//
#include <hip/hip_runtime.h>
#include <hip/hip_bf16.h>

#define NTOK 8192
#define DIM 512
#define HID 1024
#define NE 16
#define CAP 1280   // per-expert capacity; mean load = 1024, sigma ~30

typedef __attribute__((ext_vector_type(8))) short short8;
typedef __attribute__((ext_vector_type(4))) float f32x4;

static __device__ __forceinline__ unsigned short f2bf(float f) {
    __hip_bfloat16 h = __float2bfloat16(f);
    return __builtin_bit_cast(unsigned short, h);
}

// async global->LDS, 16B per lane; LDS dst = wave-uniform base + lane*16.
// Global addresses MUST be lane-linear within 8-lane row groups for DMA coalescing.
static __device__ __forceinline__ void gl_lds16(const unsigned short* g, unsigned short* l) {
    __builtin_amdgcn_global_load_lds(
        (const __attribute__((address_space(1))) unsigned int*)g,
        (__attribute__((address_space(3))) unsigned int*)l, 16, 0, 0);
}

// tanh-approx GELU via sigmoid identity: 0.5*(1+tanh(a)) = sigmoid(2a).
// max |err| vs exact erf-GELU ~3e-3.
static __device__ __forceinline__ float gelu_f(float v) {
    float u = v * (0.7978845608f + 0.0356774081f * v * v);  // sqrt(2/pi)*(v+0.044715 v^3)
    return v / (1.0f + __expf(-2.0f * u));
}

// src: [R][C] fp32 (one expert per blockIdx.z) -> dst: [C][R] bf16
__global__ void transpose_cvt(const float* __restrict__ src, unsigned short* __restrict__ dst,
                              int R, int C) {
    __shared__ float tile[32][33];
    int e = blockIdx.z;
    src += (size_t)e * R * C;
    dst += (size_t)e * R * C;
    int c0 = blockIdx.x * 32, r0 = blockIdx.y * 32;
    int tx = threadIdx.x, ty = threadIdx.y;  // (32,8)
    #pragma unroll
    for (int i = 0; i < 32; i += 8)
        tile[ty + i][tx] = src[(size_t)(r0 + ty + i) * C + c0 + tx];
    __syncthreads();
    #pragma unroll
    for (int i = 0; i < 32; i += 8)
        dst[(size_t)(c0 + ty + i) * R + r0 + tx] = f2bf(tile[tx][ty + i]);
}

// one thread per token: scan its 16 scores, assign slot 0/1 in e-order
__global__ void route_fill(const float* __restrict__ routing, int* __restrict__ cnt,
                           int* __restrict__ sidx, float* __restrict__ wtb) {
    int n = blockIdx.x * blockDim.x + threadIdx.x;
    if (n >= NTOK) return;
    int slot = 0;
    #pragma unroll
    for (int e = 0; e < NE; e++) {
        float r = routing[n * NE + e];
        if (r != 0.0f) {
            if (slot < 2) {
                int pos = atomicAdd(&cnt[e], 1);
                if (pos < CAP) {
                    sidx[e * CAP + pos] = n * 2 + slot;
                    wtb[e * CAP + pos] = r;
                }
            }
            slot++;
        }
    }
}

// one block (128 thr) per (expert,row); valid rows gathered+converted, pad rows zeroed
__global__ void gather_x(const float* __restrict__ x, const int* __restrict__ cnt,
                         const int* __restrict__ sidx, unsigned short* __restrict__ xg) {
    int b = blockIdx.x;              // e*CAP + row
    int e = b / CAP, row = b - e * CAP;
    int t = threadIdx.x;             // 128 threads * 4 floats = 512
    int c = cnt[e]; c = c > CAP ? CAP : c;
    ushort4 o;
    if (row < c) {
        int n = sidx[b] >> 1;
        float4 v = ((const float4*)(x + (size_t)n * DIM))[t];
        o.x = f2bf(v.x); o.y = f2bf(v.y); o.z = f2bf(v.z); o.w = f2bf(v.w);
    } else {
        o.x = 0; o.y = 0; o.z = 0; o.w = 0;
    }
    ((ushort4*)(xg + (size_t)b * DIM))[t] = o;
}

// 128x128 tile, BK=64, 4 waves (2x2), each wave 4x4 of 16x16x32 bf16 MFMA.
// A: MxK row-major, B: NxK row-major (both K-contig). Linear LDS layout
// (row*64 elems), lane-linear global_load_lds staging (m97 structure).
template <int K>
__device__ __forceinline__ void mfma_main(const unsigned short* __restrict__ A,
                                          const unsigned short* __restrict__ B,
                                          unsigned short* As, unsigned short* Bs,
                                          f32x4 acc[4][4]) {
    int t = threadIdx.x;
    int wave = t >> 6, lane = t & 63;
    int wm = wave >> 1, wn = wave & 1;
    int quad = lane >> 4, l16 = lane & 15;
    int lr = lane >> 3;                 // row within 8-row staging group
    int col = (lane & 7) << 3;          // linear chunk -> coalesced global reads
    for (int kc = 0; kc < K; kc += 64) {
        __syncthreads();
        #pragma unroll
        for (int j = 0; j < 4; j++) {
            int rb = wave * 32 + j * 8;
            gl_lds16(A + (size_t)(rb + lr) * K + kc + col, As + rb * 64);
            gl_lds16(B + (size_t)(rb + lr) * K + kc + col, Bs + rb * 64);
        }
        __syncthreads();
        #pragma unroll
        for (int kk = 0; kk < 64; kk += 32) {
            short8 av[4], bv[4];
            #pragma unroll
            for (int mt = 0; mt < 4; mt++)
                av[mt] = *(const short8*)(&As[(wm * 64 + mt * 16 + l16) * 64 + kk + quad * 8]);
            #pragma unroll
            for (int nt = 0; nt < 4; nt++)
                bv[nt] = *(const short8*)(&Bs[(wn * 64 + nt * 16 + l16) * 64 + kk + quad * 8]);
            #pragma unroll
            for (int mt = 0; mt < 4; mt++)
                #pragma unroll
                for (int nt = 0; nt < 4; nt++)
                    acc[mt][nt] = __builtin_amdgcn_mfma_f32_16x16x32_bf16(
                        av[mt], bv[nt], acc[mt][nt], 0, 0, 0);
        }
    }
}

__global__ __launch_bounds__(256) void gemm1_gelu(
    const unsigned short* __restrict__ xg, const unsigned short* __restrict__ w1t,
    const float* __restrict__ b1, const int* __restrict__ cnt,
    unsigned short* __restrict__ hbuf) {
    __shared__ __align__(16) unsigned short As[128 * 64];
    __shared__ __align__(16) unsigned short Bs[128 * 64];
    int e = blockIdx.z;
    int c = cnt[e]; c = c > CAP ? CAP : c;
    int m0 = blockIdx.y * 128;
    if (m0 >= c) return;
    int n0 = blockIdx.x * 128;
    const unsigned short* A = xg + ((size_t)e * CAP + m0) * DIM;
    const unsigned short* B = w1t + ((size_t)e * HID + n0) * DIM;
    f32x4 z = {0.f, 0.f, 0.f, 0.f};
    f32x4 acc[4][4];
    #pragma unroll
    for (int mt = 0; mt < 4; mt++)
        #pragma unroll
        for (int nt = 0; nt < 4; nt++) acc[mt][nt] = z;
    mfma_main<DIM>(A, B, As, Bs, acc);
    int t = threadIdx.x;
    int wave = t >> 6, lane = t & 63;
    int wm = wave >> 1, wn = wave & 1, quad = lane >> 4, l16 = lane & 15;
    #pragma unroll
    for (int nt = 0; nt < 4; nt++) {
        int gn = n0 + wn * 64 + nt * 16 + l16;
        float bias = b1[e * HID + gn];
        #pragma unroll
        for (int mt = 0; mt < 4; mt++) {
            #pragma unroll
            for (int r = 0; r < 4; r++) {
                int gm = m0 + wm * 64 + mt * 16 + quad * 4 + r;
                float v = acc[mt][nt][r] + bias;
                hbuf[((size_t)e * CAP + gm) * HID + gn] = f2bf(gelu_f(v));
            }
        }
    }
}

__global__ __launch_bounds__(256) void gemm2_store(
    const unsigned short* __restrict__ hbuf, const unsigned short* __restrict__ w2t,
    const float* __restrict__ b2, const int* __restrict__ cnt,
    const int* __restrict__ sidx, const float* __restrict__ wtb,
    float* __restrict__ ybuf) {
    __shared__ __align__(16) unsigned short As[128 * 64];
    __shared__ __align__(16) unsigned short Bs[128 * 64];
    int e = blockIdx.z;
    int c = cnt[e]; c = c > CAP ? CAP : c;
    int m0 = blockIdx.y * 128;
    if (m0 >= c) return;
    int n0 = blockIdx.x * 128;
    const unsigned short* A = hbuf + ((size_t)e * CAP + m0) * HID;
    const unsigned short* B = w2t + ((size_t)e * DIM + n0) * HID;
    f32x4 z = {0.f, 0.f, 0.f, 0.f};
    f32x4 acc[4][4];
    #pragma unroll
    for (int mt = 0; mt < 4; mt++)
        #pragma unroll
        for (int nt = 0; nt < 4; nt++) acc[mt][nt] = z;
    mfma_main<HID>(A, B, As, Bs, acc);
    int t = threadIdx.x;
    int wave = t >> 6, lane = t & 63;
    int wm = wave >> 1, wn = wave & 1, quad = lane >> 4, l16 = lane & 15;
    #pragma unroll
    for (int mt = 0; mt < 4; mt++) {
        #pragma unroll
        for (int r = 0; r < 4; r++) {
            int gm = m0 + wm * 64 + mt * 16 + quad * 4 + r;
            if (gm < c) {
                int si = sidx[e * CAP + gm];       // token*2 + slot
                float wgt = wtb[e * CAP + gm];
                float* yrow = ybuf + (size_t)si * DIM;
                #pragma unroll
                for (int nt = 0; nt < 4; nt++) {
                    int gn = n0 + wn * 64 + nt * 16 + l16;
                    yrow[gn] = wgt * (acc[mt][nt][r] + b2[e * DIM + gn]);
                }
            }
        }
    }
}

// out[n] = ybuf[n*2] + ybuf[n*2+1]; every (token,slot) pair is written by
// gemm2 (each token has exactly TOPK=2 experts), so no ybuf zero-init needed.
__global__ void combine(const float* __restrict__ yb, float* __restrict__ out) {
    int i = blockIdx.x * 256 + threadIdx.x;   // over NTOK * DIM/4
    int n = i >> 7, d4 = i & 127;             // DIM/4 = 128
    float4 a = ((const float4*)(yb + (size_t)(2 * n) * DIM))[d4];
    float4 b = ((const float4*)(yb + (size_t)(2 * n + 1) * DIM))[d4];
    float4 o;
    o.x = a.x + b.x; o.y = a.y + b.y; o.z = a.z + b.z; o.w = a.w + b.w;
    ((float4*)(out + (size_t)n * DIM))[d4] = o;
}

extern "C" void kernel_launch(void* const* d_in, const int* in_sizes, int n_in,
                              void* d_out, int out_size, void* d_ws, size_t ws_size,
                              hipStream_t stream) {
    const float* x       = (const float*)d_in[0];
    const float* routing = (const float*)d_in[1];
    const float* W1      = (const float*)d_in[2];
    const float* b1      = (const float*)d_in[3];
    const float* W2      = (const float*)d_in[4];
    const float* b2      = (const float*)d_in[5];
    float* out = (float*)d_out;

    // workspace carve (ws poisoned 0xAA each call)
    char* w = (char*)d_ws;
    int*   cnt  = (int*)w;                                  // 256 B
    int*   sidx = (int*)(w + 256);                          // NE*CAP*4
    float* wtb  = (float*)(w + 256 + NE * CAP * 4);         // NE*CAP*4
    char* base = w + 256 + NE * CAP * 8;
    unsigned short* xg  = (unsigned short*)base;            // 20 MiB
    unsigned short* hb  = xg + (size_t)NE * CAP * DIM;      // 40 MiB
    unsigned short* w1t = hb + (size_t)NE * CAP * HID;      // 16 MiB
    unsigned short* w2t = w1t + (size_t)NE * HID * DIM;     // 16 MiB
    float* ybuf = (float*)(w2t + (size_t)NE * DIM * HID);   // 32 MiB fp32 [NTOK][2][DIM]

    hipMemsetAsync(cnt, 0, 256, stream);

    transpose_cvt<<<dim3(HID / 32, DIM / 32, NE), dim3(32, 8), 0, stream>>>(W1, w1t, DIM, HID);
    transpose_cvt<<<dim3(DIM / 32, HID / 32, NE), dim3(32, 8), 0, stream>>>(W2, w2t, HID, DIM);

    route_fill<<<NTOK / 256, 256, 0, stream>>>(routing, cnt, sidx, wtb);
    gather_x<<<NE * CAP, 128, 0, stream>>>(x, cnt, sidx, xg);

    gemm1_gelu<<<dim3(HID / 128, CAP / 128, NE), 256, 0, stream>>>(xg, w1t, b1, cnt, hb);
    gemm2_store<<<dim3(DIM / 128, CAP / 128, NE), 256, 0, stream>>>(hb, w2t, b2, cnt, sidx, wtb, ybuf);
    combine<<<(NTOK * DIM / 4) / 256, 256, 0, stream>>>(ybuf, out);
}

// Round 4
// 254.248 us; speedup vs baseline: 1.3873x; 1.0796x over previous
//
#include <hip/hip_runtime.h>
#include <hip/hip_bf16.h>

#define NTOK 8192
#define DIM 512
#define HID 1024
#define NE 16
#define CAP 1280   // per-expert capacity; mean load = 1024, sigma ~30

typedef __attribute__((ext_vector_type(8))) short short8;
typedef __attribute__((ext_vector_type(4))) float f32x4;

static __device__ __forceinline__ unsigned short f2bf(float f) {
    __hip_bfloat16 h = __float2bfloat16(f);
    return __builtin_bit_cast(unsigned short, h);
}

// async global->LDS, 16B per lane; LDS dst = wave-uniform base + lane*16.
// Global addresses lane-linear within 8-lane row groups for DMA coalescing.
static __device__ __forceinline__ void gl_lds16(const unsigned short* g, unsigned short* l) {
    __builtin_amdgcn_global_load_lds(
        (const __attribute__((address_space(1))) unsigned int*)g,
        (__attribute__((address_space(3))) unsigned int*)l, 16, 0, 0);
}

// tanh-approx GELU; max |err| vs exact erf-GELU ~3e-3.
static __device__ __forceinline__ float gelu_f(float v) {
    float u = v * (0.7978845608f + 0.0356774081f * v * v);
    return v / (1.0f + __expf(-2.0f * u));
}

// Both weight transposes in one dispatch. b<8192: W1 (R=DIM,C=HID); else W2.
__global__ void transpose_cvt2(const float* __restrict__ W1, const float* __restrict__ W2,
                               unsigned short* __restrict__ w1t, unsigned short* __restrict__ w2t) {
    __shared__ float tile[32][33];
    int b = blockIdx.x;
    const float* src; unsigned short* dst; int R, C, bx, by;
    if (b < 8192) {               // W1: per-e grid 32x16
        int e = b >> 9, rem = b & 511; bx = rem & 31; by = rem >> 5;
        R = DIM; C = HID;
        src = W1 + (size_t)e * R * C; dst = w1t + (size_t)e * R * C;
    } else {                      // W2: per-e grid 16x32
        int bb = b - 8192;
        int e = bb >> 9, rem = bb & 511; bx = rem & 15; by = rem >> 4;
        R = HID; C = DIM;
        src = W2 + (size_t)e * R * C; dst = w2t + (size_t)e * R * C;
    }
    int c0 = bx * 32, r0 = by * 32;
    int tx = threadIdx.x, ty = threadIdx.y;  // (32,8)
    #pragma unroll
    for (int i = 0; i < 32; i += 8)
        tile[ty + i][tx] = src[(size_t)(r0 + ty + i) * C + c0 + tx];
    __syncthreads();
    #pragma unroll
    for (int i = 0; i < 32; i += 8)
        dst[(size_t)(c0 + ty + i) * R + r0 + tx] = f2bf(tile[tx][ty + i]);
}

// LDS-aggregated routing: per-block local counts, 16 global atomics per block.
// Order within an expert is arbitrary (sidx carries token id) - harmless.
__global__ __launch_bounds__(256) void route_fill(const float* __restrict__ routing,
                                                  int* __restrict__ cnt,
                                                  int* __restrict__ sidx,
                                                  float* __restrict__ wtb) {
    __shared__ int lcnt[NE], lbase[NE];
    int t = threadIdx.x;
    int n = blockIdx.x * 256 + t;
    if (t < NE) lcnt[t] = 0;
    __syncthreads();
    int mye[2]; float myw[2]; int mypos[2]; int slot = 0;
    #pragma unroll
    for (int e = 0; e < NE; e++) {
        float r = routing[n * NE + e];
        if (r != 0.0f && slot < 2) {
            mye[slot] = e; myw[slot] = r;
            mypos[slot] = atomicAdd(&lcnt[e], 1);
            slot++;
        }
    }
    __syncthreads();
    if (t < NE) lbase[t] = atomicAdd(&cnt[t], lcnt[t]);
    __syncthreads();
    for (int s = 0; s < slot; s++) {
        int e = mye[s];
        int p = lbase[e] + mypos[s];
        if (p < CAP) { sidx[e * CAP + p] = n * 2 + s; wtb[e * CAP + p] = myw[s]; }
    }
}

// one block (128 thr) per (expert,row); valid rows gathered+converted, pad rows zeroed
__global__ void gather_x(const float* __restrict__ x, const int* __restrict__ cnt,
                         const int* __restrict__ sidx, unsigned short* __restrict__ xg) {
    int b = blockIdx.x;              // e*CAP + row
    int e = b / CAP, row = b - e * CAP;
    int t = threadIdx.x;             // 128 threads * 4 floats = 512
    int c = cnt[e]; c = c > CAP ? CAP : c;
    ushort4 o;
    if (row < c) {
        int n = sidx[b] >> 1;
        float4 v = ((const float4*)(x + (size_t)n * DIM))[t];
        o.x = f2bf(v.x); o.y = f2bf(v.y); o.z = f2bf(v.z); o.w = f2bf(v.w);
    } else {
        o.x = 0; o.y = 0; o.z = 0; o.w = 0;
    }
    ((ushort4*)(xg + (size_t)b * DIM))[t] = o;
}

// ---- single-buffered main loop (control; used by gemm1) ----
template <int K>
__device__ __forceinline__ void mfma_main(const unsigned short* __restrict__ A,
                                          const unsigned short* __restrict__ B,
                                          unsigned short* As, unsigned short* Bs,
                                          f32x4 acc[4][4]) {
    int t = threadIdx.x;
    int wave = t >> 6, lane = t & 63;
    int wm = wave >> 1, wn = wave & 1;
    int quad = lane >> 4, l16 = lane & 15;
    int lr = lane >> 3;
    int col = (lane & 7) << 3;
    for (int kc = 0; kc < K; kc += 64) {
        __syncthreads();
        #pragma unroll
        for (int j = 0; j < 4; j++) {
            int rb = wave * 32 + j * 8;
            gl_lds16(A + (size_t)(rb + lr) * K + kc + col, As + rb * 64);
            gl_lds16(B + (size_t)(rb + lr) * K + kc + col, Bs + rb * 64);
        }
        __syncthreads();
        #pragma unroll
        for (int kk = 0; kk < 64; kk += 32) {
            short8 av[4], bv[4];
            #pragma unroll
            for (int mt = 0; mt < 4; mt++)
                av[mt] = *(const short8*)(&As[(wm * 64 + mt * 16 + l16) * 64 + kk + quad * 8]);
            #pragma unroll
            for (int nt = 0; nt < 4; nt++)
                bv[nt] = *(const short8*)(&Bs[(wn * 64 + nt * 16 + l16) * 64 + kk + quad * 8]);
            #pragma unroll
            for (int mt = 0; mt < 4; mt++)
                #pragma unroll
                for (int nt = 0; nt < 4; nt++)
                    acc[mt][nt] = __builtin_amdgcn_mfma_f32_16x16x32_bf16(
                        av[mt], bv[nt], acc[mt][nt], 0, 0, 0);
        }
    }
}

// ---- double-buffered main loop (experiment; used by gemm2) ----
// One barrier per K-iter: prefetch next tile into buf^1, compute on buf,
// barrier drains the prefetch AFTER compute -> fetch/compute overlap.
template <int K>
__device__ __forceinline__ void mfma_main_db(const unsigned short* __restrict__ A,
                                             const unsigned short* __restrict__ B,
                                             unsigned short (*As)[128 * 64],
                                             unsigned short (*Bs)[128 * 64],
                                             f32x4 acc[4][4]) {
    int t = threadIdx.x;
    int wave = t >> 6, lane = t & 63;
    int wm = wave >> 1, wn = wave & 1;
    int quad = lane >> 4, l16 = lane & 15;
    int lr = lane >> 3;
    int col = (lane & 7) << 3;
    #pragma unroll
    for (int j = 0; j < 4; j++) {
        int rb = wave * 32 + j * 8;
        gl_lds16(A + (size_t)(rb + lr) * K + col, As[0] + rb * 64);
        gl_lds16(B + (size_t)(rb + lr) * K + col, Bs[0] + rb * 64);
    }
    __syncthreads();
    int cur = 0;
    for (int kc = 64; kc <= K; kc += 64) {
        if (kc < K) {
            #pragma unroll
            for (int j = 0; j < 4; j++) {
                int rb = wave * 32 + j * 8;
                gl_lds16(A + (size_t)(rb + lr) * K + kc + col, As[cur ^ 1] + rb * 64);
                gl_lds16(B + (size_t)(rb + lr) * K + kc + col, Bs[cur ^ 1] + rb * 64);
            }
        }
        #pragma unroll
        for (int kk = 0; kk < 64; kk += 32) {
            short8 av[4], bv[4];
            #pragma unroll
            for (int mt = 0; mt < 4; mt++)
                av[mt] = *(const short8*)(&As[cur][(wm * 64 + mt * 16 + l16) * 64 + kk + quad * 8]);
            #pragma unroll
            for (int nt = 0; nt < 4; nt++)
                bv[nt] = *(const short8*)(&Bs[cur][(wn * 64 + nt * 16 + l16) * 64 + kk + quad * 8]);
            #pragma unroll
            for (int mt = 0; mt < 4; mt++)
                #pragma unroll
                for (int nt = 0; nt < 4; nt++)
                    acc[mt][nt] = __builtin_amdgcn_mfma_f32_16x16x32_bf16(
                        av[mt], bv[nt], acc[mt][nt], 0, 0, 0);
        }
        __syncthreads();   // drains prefetch (vmcnt) + guards buffer reuse
        cur ^= 1;
    }
}

__global__ __launch_bounds__(256) void gemm1_gelu(
    const unsigned short* __restrict__ xg, const unsigned short* __restrict__ w1t,
    const float* __restrict__ b1, const int* __restrict__ cnt,
    unsigned short* __restrict__ hbuf) {
    __shared__ __align__(16) unsigned short As[128 * 64];
    __shared__ __align__(16) unsigned short Bs[128 * 64];
    int e = blockIdx.z;
    int c = cnt[e]; c = c > CAP ? CAP : c;
    int m0 = blockIdx.y * 128;
    if (m0 >= c) return;
    int n0 = blockIdx.x * 128;
    const unsigned short* A = xg + ((size_t)e * CAP + m0) * DIM;
    const unsigned short* B = w1t + ((size_t)e * HID + n0) * DIM;
    f32x4 z = {0.f, 0.f, 0.f, 0.f};
    f32x4 acc[4][4];
    #pragma unroll
    for (int mt = 0; mt < 4; mt++)
        #pragma unroll
        for (int nt = 0; nt < 4; nt++) acc[mt][nt] = z;
    mfma_main<DIM>(A, B, As, Bs, acc);
    int t = threadIdx.x;
    int wave = t >> 6, lane = t & 63;
    int wm = wave >> 1, wn = wave & 1, quad = lane >> 4, l16 = lane & 15;
    #pragma unroll
    for (int nt = 0; nt < 4; nt++) {
        int gn = n0 + wn * 64 + nt * 16 + l16;
        float bias = b1[e * HID + gn];
        #pragma unroll
        for (int mt = 0; mt < 4; mt++) {
            #pragma unroll
            for (int r = 0; r < 4; r++) {
                int gm = m0 + wm * 64 + mt * 16 + quad * 4 + r;
                float v = acc[mt][nt][r] + bias;
                hbuf[((size_t)e * CAP + gm) * HID + gn] = f2bf(gelu_f(v));
            }
        }
    }
}

__global__ __launch_bounds__(256) void gemm2_store(
    const unsigned short* __restrict__ hbuf, const unsigned short* __restrict__ w2t,
    const float* __restrict__ b2, const int* __restrict__ cnt,
    const int* __restrict__ sidx, const float* __restrict__ wtb,
    float* __restrict__ ybuf) {
    __shared__ __align__(16) unsigned short As[2][128 * 64];
    __shared__ __align__(16) unsigned short Bs[2][128 * 64];
    int e = blockIdx.z;
    int c = cnt[e]; c = c > CAP ? CAP : c;
    int m0 = blockIdx.y * 128;
    if (m0 >= c) return;
    int n0 = blockIdx.x * 128;
    const unsigned short* A = hbuf + ((size_t)e * CAP + m0) * HID;
    const unsigned short* B = w2t + ((size_t)e * DIM + n0) * HID;
    f32x4 z = {0.f, 0.f, 0.f, 0.f};
    f32x4 acc[4][4];
    #pragma unroll
    for (int mt = 0; mt < 4; mt++)
        #pragma unroll
        for (int nt = 0; nt < 4; nt++) acc[mt][nt] = z;
    mfma_main_db<HID>(A, B, As, Bs, acc);
    int t = threadIdx.x;
    int wave = t >> 6, lane = t & 63;
    int wm = wave >> 1, wn = wave & 1, quad = lane >> 4, l16 = lane & 15;
    #pragma unroll
    for (int mt = 0; mt < 4; mt++) {
        #pragma unroll
        for (int r = 0; r < 4; r++) {
            int gm = m0 + wm * 64 + mt * 16 + quad * 4 + r;
            if (gm < c) {
                int si = sidx[e * CAP + gm];       // token*2 + slot
                float wgt = wtb[e * CAP + gm];
                float* yrow = ybuf + (size_t)si * DIM;
                #pragma unroll
                for (int nt = 0; nt < 4; nt++) {
                    int gn = n0 + wn * 64 + nt * 16 + l16;
                    yrow[gn] = wgt * (acc[mt][nt][r] + b2[e * DIM + gn]);
                }
            }
        }
    }
}

// out[n] = ybuf[n*2] + ybuf[n*2+1]; both slots always written (TOPK=2).
__global__ void combine(const float* __restrict__ yb, float* __restrict__ out) {
    int i = blockIdx.x * 256 + threadIdx.x;   // over NTOK * DIM/4
    int n = i >> 7, d4 = i & 127;             // DIM/4 = 128
    float4 a = ((const float4*)(yb + (size_t)(2 * n) * DIM))[d4];
    float4 b = ((const float4*)(yb + (size_t)(2 * n + 1) * DIM))[d4];
    float4 o;
    o.x = a.x + b.x; o.y = a.y + b.y; o.z = a.z + b.z; o.w = a.w + b.w;
    ((float4*)(out + (size_t)n * DIM))[d4] = o;
}

extern "C" void kernel_launch(void* const* d_in, const int* in_sizes, int n_in,
                              void* d_out, int out_size, void* d_ws, size_t ws_size,
                              hipStream_t stream) {
    const float* x       = (const float*)d_in[0];
    const float* routing = (const float*)d_in[1];
    const float* W1      = (const float*)d_in[2];
    const float* b1      = (const float*)d_in[3];
    const float* W2      = (const float*)d_in[4];
    const float* b2      = (const float*)d_in[5];
    float* out = (float*)d_out;

    // workspace carve (ws poisoned 0xAA each call)
    char* w = (char*)d_ws;
    int*   cnt  = (int*)w;                                  // 256 B
    int*   sidx = (int*)(w + 256);                          // NE*CAP*4
    float* wtb  = (float*)(w + 256 + NE * CAP * 4);         // NE*CAP*4
    char* base = w + 256 + NE * CAP * 8;
    unsigned short* xg  = (unsigned short*)base;            // 20 MiB
    unsigned short* hb  = xg + (size_t)NE * CAP * DIM;      // 40 MiB
    unsigned short* w1t = hb + (size_t)NE * CAP * HID;      // 16 MiB
    unsigned short* w2t = w1t + (size_t)NE * HID * DIM;     // 16 MiB
    float* ybuf = (float*)(w2t + (size_t)NE * DIM * HID);   // 32 MiB fp32 [NTOK][2][DIM]

    hipMemsetAsync(cnt, 0, 256, stream);

    transpose_cvt2<<<16384, dim3(32, 8), 0, stream>>>(W1, W2, w1t, w2t);

    route_fill<<<NTOK / 256, 256, 0, stream>>>(routing, cnt, sidx, wtb);
    gather_x<<<NE * CAP, 128, 0, stream>>>(x, cnt, sidx, xg);

    gemm1_gelu<<<dim3(HID / 128, CAP / 128, NE), 256, 0, stream>>>(xg, w1t, b1, cnt, hb);
    gemm2_store<<<dim3(DIM / 128, CAP / 128, NE), 256, 0, stream>>>(hb, w2t, b2, cnt, sidx, wtb, ybuf);
    combine<<<(NTOK * DIM / 4) / 256, 256, 0, stream>>>(ybuf, out);
}

// Round 5
// 226.845 us; speedup vs baseline: 1.5549x; 1.1208x over previous
//
#include <hip/hip_runtime.h>
#include <hip/hip_bf16.h>

#define NTOK 8192
#define DIM 512
#define HID 1024
#define NE 16
#define CAP 1280   // per-expert capacity; mean load = 1024, sigma ~30
#define MT 20      // m-tiles per expert (CAP/64)

typedef __attribute__((ext_vector_type(8))) short short8;
typedef __attribute__((ext_vector_type(4))) float f32x4;

static __device__ __forceinline__ unsigned short f2bf(float f) {
    __hip_bfloat16 h = __float2bfloat16(f);
    return __builtin_bit_cast(unsigned short, h);
}

// async global->LDS, 16B per lane; LDS dst = wave-uniform base + lane*16.
static __device__ __forceinline__ void gl_lds16(const unsigned short* g, unsigned short* l) {
    __builtin_amdgcn_global_load_lds(
        (const __attribute__((address_space(1))) unsigned int*)g,
        (__attribute__((address_space(3))) unsigned int*)l, 16, 0, 0);
}

// tanh-approx GELU; max |err| vs exact erf-GELU ~3e-3.
static __device__ __forceinline__ float gelu_f(float v) {
    float u = v * (0.7978845608f + 0.0356774081f * v * v);
    return v / (1.0f + __expf(-2.0f * u));
}

// Both weight transposes in one dispatch. b<8192: W1 (R=DIM,C=HID); else W2.
__global__ void transpose_cvt2(const float* __restrict__ W1, const float* __restrict__ W2,
                               unsigned short* __restrict__ w1t, unsigned short* __restrict__ w2t) {
    __shared__ float tile[32][33];
    int b = blockIdx.x;
    const float* src; unsigned short* dst; int R, C, bx, by;
    if (b < 8192) {               // W1: per-e grid 32x16
        int e = b >> 9, rem = b & 511; bx = rem & 31; by = rem >> 5;
        R = DIM; C = HID;
        src = W1 + (size_t)e * R * C; dst = w1t + (size_t)e * R * C;
    } else {                      // W2: per-e grid 16x32
        int bb = b - 8192;
        int e = bb >> 9, rem = bb & 511; bx = rem & 15; by = rem >> 4;
        R = HID; C = DIM;
        src = W2 + (size_t)e * R * C; dst = w2t + (size_t)e * R * C;
    }
    int c0 = bx * 32, r0 = by * 32;
    int tx = threadIdx.x, ty = threadIdx.y;  // (32,8)
    #pragma unroll
    for (int i = 0; i < 32; i += 8)
        tile[ty + i][tx] = src[(size_t)(r0 + ty + i) * C + c0 + tx];
    __syncthreads();
    #pragma unroll
    for (int i = 0; i < 32; i += 8)
        dst[(size_t)(c0 + ty + i) * R + r0 + tx] = f2bf(tile[tx][ty + i]);
}

// LDS-aggregated routing: per-block local counts, 16 global atomics per block.
__global__ __launch_bounds__(256) void route_fill(const float* __restrict__ routing,
                                                  int* __restrict__ cnt,
                                                  int* __restrict__ sidx,
                                                  float* __restrict__ wtb) {
    __shared__ int lcnt[NE], lbase[NE];
    int t = threadIdx.x;
    int n = blockIdx.x * 256 + t;
    if (t < NE) lcnt[t] = 0;
    __syncthreads();
    int mye[2]; float myw[2]; int mypos[2]; int slot = 0;
    #pragma unroll
    for (int e = 0; e < NE; e++) {
        float r = routing[n * NE + e];
        if (r != 0.0f && slot < 2) {
            mye[slot] = e; myw[slot] = r;
            mypos[slot] = atomicAdd(&lcnt[e], 1);
            slot++;
        }
    }
    __syncthreads();
    if (t < NE) lbase[t] = atomicAdd(&cnt[t], lcnt[t]);
    __syncthreads();
    for (int s = 0; s < slot; s++) {
        int e = mye[s];
        int p = lbase[e] + mypos[s];
        if (p < CAP) { sidx[e * CAP + p] = n * 2 + s; wtb[e * CAP + p] = myw[s]; }
    }
}

// one block (128 thr) per (expert,row); valid rows gathered+converted, pad rows zeroed
__global__ void gather_x(const float* __restrict__ x, const int* __restrict__ cnt,
                         const int* __restrict__ sidx, unsigned short* __restrict__ xg) {
    int b = blockIdx.x;              // e*CAP + row
    int e = b / CAP, row = b - e * CAP;
    int t = threadIdx.x;             // 128 threads * 4 floats = 512
    int c = cnt[e]; c = c > CAP ? CAP : c;
    ushort4 o;
    if (row < c) {
        int n = sidx[b] >> 1;
        float4 v = ((const float4*)(x + (size_t)n * DIM))[t];
        o.x = f2bf(v.x); o.y = f2bf(v.y); o.z = f2bf(v.z); o.w = f2bf(v.w);
    } else {
        o.x = 0; o.y = 0; o.z = 0; o.w = 0;
    }
    ((ushort4*)(xg + (size_t)b * DIM))[t] = o;
}

// 64x128 tile, BK=64, 4 waves (2x2): wave covers 32 rows x 64 cols,
// each wave 2x4 of 16x16x32 bf16 MFMA. A: MxK row-major, B: NxK row-major.
// Linear LDS (row*64), lane-linear global_load_lds staging.
template <int K>
__device__ __forceinline__ void mfma_main64(const unsigned short* __restrict__ A,
                                            const unsigned short* __restrict__ B,
                                            unsigned short* As, unsigned short* Bs,
                                            f32x4 acc[2][4]) {
    int t = threadIdx.x;
    int wave = t >> 6, lane = t & 63;
    int wm = wave >> 1, wn = wave & 1;
    int quad = lane >> 4, l16 = lane & 15;
    int lr = lane >> 3;
    int col = (lane & 7) << 3;
    for (int kc = 0; kc < K; kc += 64) {
        __syncthreads();
        #pragma unroll
        for (int j = 0; j < 2; j++) {       // A: 64 rows, 8 ops total
            int rb = wave * 16 + j * 8;
            gl_lds16(A + (size_t)(rb + lr) * K + kc + col, As + rb * 64);
        }
        #pragma unroll
        for (int j = 0; j < 4; j++) {       // B: 128 rows, 16 ops total
            int rb = wave * 32 + j * 8;
            gl_lds16(B + (size_t)(rb + lr) * K + kc + col, Bs + rb * 64);
        }
        __syncthreads();
        #pragma unroll
        for (int kk = 0; kk < 64; kk += 32) {
            short8 av[2], bv[4];
            #pragma unroll
            for (int mt = 0; mt < 2; mt++)
                av[mt] = *(const short8*)(&As[(wm * 32 + mt * 16 + l16) * 64 + kk + quad * 8]);
            #pragma unroll
            for (int nt = 0; nt < 4; nt++)
                bv[nt] = *(const short8*)(&Bs[(wn * 64 + nt * 16 + l16) * 64 + kk + quad * 8]);
            #pragma unroll
            for (int mt = 0; mt < 2; mt++)
                #pragma unroll
                for (int nt = 0; nt < 4; nt++)
                    acc[mt][nt] = __builtin_amdgcn_mfma_f32_16x16x32_bf16(
                        av[mt], bv[nt], acc[mt][nt], 0, 0, 0);
        }
    }
}

// XCD-swizzled 1D grid (NT n-tiles): all NT n-blocks of one (e,m) A-panel get
// flat ids congruent mod 8 -> same XCD under round-robin -> A fetched once/XCD.
// L = (pi%8) + 8*(NT*(pi/8) + n), pi = e*MT + m. Decode below is the inverse.

__global__ __launch_bounds__(256, 5) void gemm1_gelu(
    const unsigned short* __restrict__ xg, const unsigned short* __restrict__ w1t,
    const float* __restrict__ b1, const int* __restrict__ cnt,
    unsigned short* __restrict__ hbuf) {
    __shared__ __align__(16) unsigned short As[64 * 64];
    __shared__ __align__(16) unsigned short Bs[128 * 64];
    int L = blockIdx.x;                      // 2560, NT=8
    int cc = L & 7, n = (L >> 3) & 7, g = L >> 6;
    int pi = cc + (g << 3);                  // [0,320)
    int e = pi / MT, m = pi % MT;
    int c = cnt[e]; c = c > CAP ? CAP : c;
    int m0 = m * 64;
    if (m0 >= c) return;
    int n0 = n * 128;
    const unsigned short* A = xg + ((size_t)e * CAP + m0) * DIM;
    const unsigned short* B = w1t + ((size_t)e * HID + n0) * DIM;
    f32x4 z = {0.f, 0.f, 0.f, 0.f};
    f32x4 acc[2][4];
    #pragma unroll
    for (int mt = 0; mt < 2; mt++)
        #pragma unroll
        for (int nt = 0; nt < 4; nt++) acc[mt][nt] = z;
    mfma_main64<DIM>(A, B, As, Bs, acc);
    int t = threadIdx.x;
    int wave = t >> 6, lane = t & 63;
    int wm = wave >> 1, wn = wave & 1, quad = lane >> 4, l16 = lane & 15;
    #pragma unroll
    for (int nt = 0; nt < 4; nt++) {
        int gn = n0 + wn * 64 + nt * 16 + l16;
        float bias = b1[e * HID + gn];
        #pragma unroll
        for (int mt = 0; mt < 2; mt++) {
            #pragma unroll
            for (int r = 0; r < 4; r++) {
                int gm = m0 + wm * 32 + mt * 16 + quad * 4 + r;
                float v = acc[mt][nt][r] + bias;
                hbuf[((size_t)e * CAP + gm) * HID + gn] = f2bf(gelu_f(v));
            }
        }
    }
}

__global__ __launch_bounds__(256, 5) void gemm2_store(
    const unsigned short* __restrict__ hbuf, const unsigned short* __restrict__ w2t,
    const float* __restrict__ b2, const int* __restrict__ cnt,
    const int* __restrict__ sidx, const float* __restrict__ wtb,
    float* __restrict__ ybuf) {
    __shared__ __align__(16) unsigned short As[64 * 64];
    __shared__ __align__(16) unsigned short Bs[128 * 64];
    int L = blockIdx.x;                      // 1280, NT=4
    int cc = L & 7, n = (L >> 3) & 3, g = L >> 5;
    int pi = cc + (g << 3);                  // [0,320)
    int e = pi / MT, m = pi % MT;
    int c = cnt[e]; c = c > CAP ? CAP : c;
    int m0 = m * 64;
    if (m0 >= c) return;
    int n0 = n * 128;
    const unsigned short* A = hbuf + ((size_t)e * CAP + m0) * HID;
    const unsigned short* B = w2t + ((size_t)e * DIM + n0) * HID;
    f32x4 z = {0.f, 0.f, 0.f, 0.f};
    f32x4 acc[2][4];
    #pragma unroll
    for (int mt = 0; mt < 2; mt++)
        #pragma unroll
        for (int nt = 0; nt < 4; nt++) acc[mt][nt] = z;
    mfma_main64<HID>(A, B, As, Bs, acc);
    int t = threadIdx.x;
    int wave = t >> 6, lane = t & 63;
    int wm = wave >> 1, wn = wave & 1, quad = lane >> 4, l16 = lane & 15;
    #pragma unroll
    for (int mt = 0; mt < 2; mt++) {
        #pragma unroll
        for (int r = 0; r < 4; r++) {
            int gm = m0 + wm * 32 + mt * 16 + quad * 4 + r;
            if (gm < c) {
                int si = sidx[e * CAP + gm];       // token*2 + slot
                float wgt = wtb[e * CAP + gm];
                float* yrow = ybuf + (size_t)si * DIM;
                #pragma unroll
                for (int nt = 0; nt < 4; nt++) {
                    int gn = n0 + wn * 64 + nt * 16 + l16;
                    yrow[gn] = wgt * (acc[mt][nt][r] + b2[e * DIM + gn]);
                }
            }
        }
    }
}

// out[n] = ybuf[n*2] + ybuf[n*2+1]; both slots always written (TOPK=2).
__global__ void combine(const float* __restrict__ yb, float* __restrict__ out) {
    int i = blockIdx.x * 256 + threadIdx.x;   // over NTOK * DIM/4
    int n = i >> 7, d4 = i & 127;             // DIM/4 = 128
    float4 a = ((const float4*)(yb + (size_t)(2 * n) * DIM))[d4];
    float4 b = ((const float4*)(yb + (size_t)(2 * n + 1) * DIM))[d4];
    float4 o;
    o.x = a.x + b.x; o.y = a.y + b.y; o.z = a.z + b.z; o.w = a.w + b.w;
    ((float4*)(out + (size_t)n * DIM))[d4] = o;
}

extern "C" void kernel_launch(void* const* d_in, const int* in_sizes, int n_in,
                              void* d_out, int out_size, void* d_ws, size_t ws_size,
                              hipStream_t stream) {
    const float* x       = (const float*)d_in[0];
    const float* routing = (const float*)d_in[1];
    const float* W1      = (const float*)d_in[2];
    const float* b1      = (const float*)d_in[3];
    const float* W2      = (const float*)d_in[4];
    const float* b2      = (const float*)d_in[5];
    float* out = (float*)d_out;

    // workspace carve (ws poisoned 0xAA each call)
    char* w = (char*)d_ws;
    int*   cnt  = (int*)w;                                  // 256 B
    int*   sidx = (int*)(w + 256);                          // NE*CAP*4
    float* wtb  = (float*)(w + 256 + NE * CAP * 4);         // NE*CAP*4
    char* base = w + 256 + NE * CAP * 8;
    unsigned short* xg  = (unsigned short*)base;            // 20 MiB
    unsigned short* hb  = xg + (size_t)NE * CAP * DIM;      // 40 MiB
    unsigned short* w1t = hb + (size_t)NE * CAP * HID;      // 16 MiB
    unsigned short* w2t = w1t + (size_t)NE * HID * DIM;     // 16 MiB
    float* ybuf = (float*)(w2t + (size_t)NE * DIM * HID);   // 32 MiB fp32 [NTOK][2][DIM]

    hipMemsetAsync(cnt, 0, 256, stream);

    transpose_cvt2<<<16384, dim3(32, 8), 0, stream>>>(W1, W2, w1t, w2t);

    route_fill<<<NTOK / 256, 256, 0, stream>>>(routing, cnt, sidx, wtb);
    gather_x<<<NE * CAP, 128, 0, stream>>>(x, cnt, sidx, xg);

    gemm1_gelu<<<8 * MT * NE, 256, 0, stream>>>(xg, w1t, b1, cnt, hb);
    gemm2_store<<<4 * MT * NE, 256, 0, stream>>>(hb, w2t, b2, cnt, sidx, wtb, ybuf);
    combine<<<(NTOK * DIM / 4) / 256, 256, 0, stream>>>(ybuf, out);
}